// Round 14
// baseline (222.590 us; speedup 1.0000x reference)
//
#include <hip/hip_runtime.h>

#define N_NODES 20000
#define N_EDGES 640000
#define DIM 128
#define NGRAPH 64
#define NBUCK 313          // ceil(20000/64) dst buckets of 64 nodes
#define CAP 2560           // padded records per bucket (mean 2048, 11 sigma)
#define EPB 1024           // edges per partition chunk
#define NB_PART 625        // ceil(640000/1024)
#define NB_XCONV 160
#define NB_WCONV 32

typedef __attribute__((ext_vector_type(8))) short short8;
typedef __attribute__((ext_vector_type(4))) float floatx4;

__device__ __forceinline__ unsigned int bf16rne(float f) {
    unsigned int u = __float_as_uint(f);
    return (u + 0x7FFFu + ((u >> 16) & 1u)) >> 16;
}

__device__ __forceinline__ int lowerb(const int* __restrict__ arr, int n, int v) {
    int lo = 0, hi = n;
    while (lo < hi) {
        int mid = (lo + hi) >> 1;
        if (arr[mid] < v) lo = mid + 1; else hi = mid;
    }
    return lo;
}

// ---------------------------------------------------------------------------
// K1: fused [edge partition into fixed-capacity buckets | x->bf16 convert |
// weight split-bf16 convert | params (vrel,vroot,cb3) + per-graph counts].
// record.x = (dst<<16)|src
// ---------------------------------------------------------------------------
__global__ __launch_bounds__(256) void k_part_prep(
    const int* __restrict__ src, const int* __restrict__ dst,
    const float* __restrict__ ew, const float* __restrict__ x,
    const int* __restrict__ batch,
    const float* __restrict__ W1rel, const float* __restrict__ W1root,
    const float* __restrict__ W3rel, const float* __restrict__ W3root,
    const float* __restrict__ b3, const float* __restrict__ Wlin,
    int* __restrict__ gcursor, int2* __restrict__ part,
    unsigned int* __restrict__ xb32,
    unsigned short* __restrict__ wbh, unsigned short* __restrict__ wbl,
    float* __restrict__ vrel, float* __restrict__ vroot, float* __restrict__ cb3,
    int* __restrict__ cntg) {

    const int t = threadIdx.x;
    const int blk = blockIdx.x;

    if (blk < NB_PART) {
        __shared__ int lhist[NBUCK], lbase[NBUCK], gbase[NBUCK], lcur[NBUCK];
        __shared__ int2 lrec[EPB];   // 8 KB
        for (int i = t; i < NBUCK; i += 256) lhist[i] = 0;
        __syncthreads();
        const int e0 = blk * EPB;
        const int tot = min(EPB, N_EDGES - e0);
        int mys[4], myd[4];
        float myw[4];
        for (int i = 0; i < 4; ++i) {
            int e = e0 + i * 256 + t;
            if (e < N_EDGES) {
                mys[i] = src[e];
                myd[i] = dst[e];
                myw[i] = ew[e];
                atomicAdd(&lhist[myd[i] >> 6], 1);
            } else {
                myd[i] = -1;
            }
        }
        __syncthreads();
        if (t < 64) {
            int carry = 0;
            for (int c = 0; c < 5; ++c) {
                int idx = c * 64 + t;
                int v = (idx < NBUCK) ? lhist[idx] : 0;
                int xv = v;
                for (int s = 1; s < 64; s <<= 1) {
                    int u = __shfl_up(xv, s);
                    if (t >= s) xv += u;
                }
                if (idx < NBUCK) { lbase[idx] = carry + xv - v; lcur[idx] = 0; }
                carry += __shfl(xv, 63);
            }
        }
        __syncthreads();
        for (int i = t; i < NBUCK; i += 256) {
            int c = lhist[i];
            gbase[i] = c ? (i * CAP + atomicAdd(&gcursor[i], c)) : 0;
        }
        __syncthreads();
        for (int i = 0; i < 4; ++i) {
            if (myd[i] >= 0) {
                int bb = myd[i] >> 6;
                int slot = lbase[bb] + atomicAdd(&lcur[bb], 1);
                lrec[slot] = make_int2((myd[i] << 16) | mys[i], __float_as_int(myw[i]));
            }
        }
        __syncthreads();
        for (int i = t; i < tot; i += 256) {
            int2 rc = lrec[i];
            int bb = ((unsigned)rc.x >> 16) >> 6;
            part[gbase[bb] + (i - lbase[bb])] = rc;
        }
    } else if (blk < NB_PART + NB_XCONV) {
        // x -> bf16 (rne), packed pairs
        const int b = blk - NB_PART;
        const float4* x4 = (const float4*)x;
        uint2* xh2 = (uint2*)xb32;
        for (int i = b * 256 + t; i < N_NODES * 32; i += NB_XCONV * 256) {
            float4 v = x4[i];
            uint2 hp;
            hp.x = bf16rne(v.x) | (bf16rne(v.y) << 16);
            hp.y = bf16rne(v.z) | (bf16rne(v.w) << 16);
            xh2[i] = hp;
        }
    } else if (blk < NB_PART + NB_XCONV + NB_WCONV) {
        const int b = blk - (NB_PART + NB_XCONV);
        for (int i = b * 256 + t; i < 256 * DIM; i += NB_WCONV * 256) {
            int n = i >> 7, k = i & 127;
            float v = (n < DIM) ? W1rel[n * DIM + k] : W1root[(n - DIM) * DIM + k];
            unsigned int h = bf16rne(v);
            wbh[i] = (unsigned short)h;
            wbl[i] = (unsigned short)bf16rne(v - __uint_as_float(h << 16));
        }
    } else {
        if (t < 64) {
            for (int kk = 0; kk < 2; ++kk) {
                int k = t + kk * 64;
                float sr = 0.f, so = 0.f;
                for (int h = 0; h < DIM; ++h) {
                    float wl = Wlin[h];
                    sr = fmaf(wl, W3rel[h * DIM + k], sr);
                    so = fmaf(wl, W3root[h * DIM + k], so);
                }
                vrel[k] = sr;
                vroot[k] = so;
            }
            // per-graph node counts from sorted batch
            cntg[t] = lowerb(batch, N_NODES, t + 1) - lowerb(batch, N_NODES, t);
            float c = b3[t] * Wlin[t] + b3[t + 64] * Wlin[t + 64];
            for (int m = 32; m > 0; m >>= 1) c += __shfl_xor(c, m);
            if (t == 0) cb3[0] = c;
        }
    }
}

// ---------------------------------------------------------------------------
// K2: z = A * x_bf16. Block = 4 nodes (one bucket slice); scan bucket records,
// filter into per-node LDS lists, then wave-per-node 8-deep bf16 row gather.
// z is fp32 [20032 x 128].
// ---------------------------------------------------------------------------
__global__ __launch_bounds__(256) void k_zgather(
    const int* __restrict__ gcursor, const int2* __restrict__ part,
    const unsigned int* __restrict__ xb32, float* __restrict__ z) {
    __shared__ int2 lrec[4][256];   // 8 KB
    __shared__ int lcur[4];
    const int t = threadIdx.x;
    const int w = t >> 6;
    const int lane = t & 63;
    const int nodeBase = blockIdx.x * 4;
    const int bucket = nodeBase >> 6;

    if (t < 4) lcur[t] = 0;
    __syncthreads();
    const int base = bucket * CAP;
    const int cnt = min(gcursor[bucket], CAP);
    for (int i = t; i < cnt; i += 256) {
        int2 rc = part[base + i];
        int wi = (int)((unsigned)rc.x >> 16) - nodeBase;
        if ((unsigned)wi < 4u) {
            int s = atomicAdd(&lcur[wi], 1);
            if (s < 256) lrec[wi][s] = rc;
        }
    }
    __syncthreads();

    const int node = nodeBase + w;
    if (node >= N_NODES) return;
    const int len = min(lcur[w], 256);
    float sx = 0.f, sy = 0.f;
    int j = 0;
    for (; j + 8 <= len; j += 8) {
        int2 rc[8];
        #pragma unroll
        for (int u = 0; u < 8; ++u) rc[u] = lrec[w][j + u];
        unsigned int v[8];
        #pragma unroll
        for (int u = 0; u < 8; ++u) v[u] = xb32[(size_t)(rc[u].x & 0xFFFF) * 64 + lane];
        #pragma unroll
        for (int u = 0; u < 8; ++u) {
            float ww = __int_as_float(rc[u].y);
            sx = fmaf(ww, __uint_as_float(v[u] << 16), sx);
            sy = fmaf(ww, __uint_as_float(v[u] & 0xFFFF0000u), sy);
        }
    }
    for (; j < len; ++j) {
        int2 rc = lrec[w][j];
        float ww = __int_as_float(rc.y);
        unsigned int vv = xb32[(size_t)(rc.x & 0xFFFF) * 64 + lane];
        sx = fmaf(ww, __uint_as_float(vv << 16), sx);
        sy = fmaf(ww, __uint_as_float(vv & 0xFFFF0000u), sy);
    }
    float2* z2 = (float2*)z;
    z2[(size_t)node * 64 + lane] = make_float2(sx, sy);
}

// ---------------------------------------------------------------------------
// K3: h1 = relu(z*W1rel^T + x*W1root^T + b1) with a/b dots fused in epilogue.
// grid = (313 row-tiles, 2 col-halves of 64). Two MFMA chains into one acc.
// Epilogue: a[row] += sum_col h1*vrel (atomicAdd, a zeroed by memset);
//           graph-sums of h1.vroot partials -> gsum (<=2 graphs per 64 rows).
// LDS: per-kc weight chunk, XOR-swizzled (2-way bank aliasing = free).
// ---------------------------------------------------------------------------
__global__ __launch_bounds__(256) void k_gemm_dots(
    const float* __restrict__ x, const float* __restrict__ z,
    const unsigned short* __restrict__ wbh, const unsigned short* __restrict__ wbl,
    const float* __restrict__ b1,
    const float* __restrict__ vrel, const float* __restrict__ vroot,
    const int* __restrict__ batch,
    float* __restrict__ aArr, float* __restrict__ gsum) {
    __shared__ unsigned short smem[2][128 * 32];   // [hi|lo] 8 KB each
    const int t = threadIdx.x;
    const int g = blockIdx.x;
    const int c0 = blockIdx.y * 64;

    const int lane = t & 63;
    const int m = lane & 15;
    const int q = lane >> 4;
    const int row0 = g * 64 + (t >> 6) * 16;

    floatx4 acc[4];
    #pragma unroll
    for (int i = 0; i < 4; ++i) acc[i] = (floatx4)(0.f);

    uint4* sh4 = (uint4*)smem[0];
    uint4* sl4 = (uint4*)smem[1];
    const uint4* gh = (const uint4*)wbh;
    const uint4* gl = (const uint4*)wbl;

    for (int kc = 0; kc < 4; ++kc) {
        __syncthreads();
        // stage 128 weight-rows (64 rel @ c0, 64 root @ 128+c0), k-chunk kc
        for (int i = t; i < 512; i += 256) {
            int row = i >> 2, ch = i & 3;
            int wbrow = (row < 64) ? (c0 + row) : (128 + c0 + row - 64);
            int sc = row * 4 + (ch ^ ((row >> 2) & 3));
            int gi = wbrow * 16 + kc * 4 + ch;
            sh4[sc] = gh[gi];
            sl4[sc] = gl[gi];
        }
        __syncthreads();

        // A-frags: z row (hi/lo split) and x row (hi/lo split)
        const int arow = row0 + m;
        const bool ok = arow < N_NODES;
        const float* zp = z + (size_t)arow * DIM + kc * 32 + q * 8;
        float4 z0 = ((const float4*)zp)[0];
        float4 z1 = ((const float4*)zp)[1];
        float4 x0 = make_float4(0.f, 0.f, 0.f, 0.f);
        float4 x1 = make_float4(0.f, 0.f, 0.f, 0.f);
        if (ok) {
            const float* xp = x + (size_t)arow * DIM + kc * 32 + q * 8;
            x0 = ((const float4*)xp)[0];
            x1 = ((const float4*)xp)[1];
        }
        float zf[8] = {z0.x, z0.y, z0.z, z0.w, z1.x, z1.y, z1.z, z1.w};
        float xf[8] = {x0.x, x0.y, x0.z, x0.w, x1.x, x1.y, x1.z, x1.w};
        short8 zh, zl, xh, xl;
        #pragma unroll
        for (int i = 0; i < 8; ++i) {
            unsigned int h = bf16rne(zf[i]);
            zh[i] = (short)h;
            zl[i] = (short)bf16rne(zf[i] - __uint_as_float(h << 16));
            unsigned int h2 = bf16rne(xf[i]);
            xh[i] = (short)h2;
            xl[i] = (short)bf16rne(xf[i] - __uint_as_float(h2 << 16));
        }

        const short8* SH = (const short8*)smem[0];
        const short8* SL = (const short8*)smem[1];
        #pragma unroll
        for (int nt = 0; nt < 4; ++nt) {
            int rrel = nt * 16 + m;          // rel LDS row
            int rroot = 64 + nt * 16 + m;    // root LDS row
            int cc1 = q ^ ((rrel >> 2) & 3);
            int cc2 = q ^ ((rroot >> 2) & 3);
            short8 bh = SH[rrel * 4 + cc1];
            short8 bl = SL[rrel * 4 + cc1];
            short8 ch = SH[rroot * 4 + cc2];
            short8 cl = SL[rroot * 4 + cc2];
            acc[nt] = __builtin_amdgcn_mfma_f32_16x16x32_bf16(zh, bh, acc[nt], 0, 0, 0);
            acc[nt] = __builtin_amdgcn_mfma_f32_16x16x32_bf16(zl, bh, acc[nt], 0, 0, 0);
            acc[nt] = __builtin_amdgcn_mfma_f32_16x16x32_bf16(zh, bl, acc[nt], 0, 0, 0);
            acc[nt] = __builtin_amdgcn_mfma_f32_16x16x32_bf16(xh, ch, acc[nt], 0, 0, 0);
            acc[nt] = __builtin_amdgcn_mfma_f32_16x16x32_bf16(xl, ch, acc[nt], 0, 0, 0);
            acc[nt] = __builtin_amdgcn_mfma_f32_16x16x32_bf16(xh, cl, acc[nt], 0, 0, 0);
        }
    }

    // epilogue: h1 = relu(acc + b1); pa += h1*vrel; pb += h1*vroot (per row)
    float pa[4] = {0.f, 0.f, 0.f, 0.f};
    float pb[4] = {0.f, 0.f, 0.f, 0.f};
    #pragma unroll
    for (int nt = 0; nt < 4; ++nt) {
        int col = c0 + nt * 16 + m;
        float vb = b1[col];
        float vr = vrel[col];
        float vo = vroot[col];
        #pragma unroll
        for (int reg = 0; reg < 4; ++reg) {
            float h = fmaxf(acc[nt][reg] + vb, 0.f);
            pa[reg] = fmaf(h, vr, pa[reg]);
            pb[reg] = fmaf(h, vo, pb[reg]);
        }
    }
    // reduce over the 16 cols held within each quad (lanes q*16..q*16+15)
    #pragma unroll
    for (int reg = 0; reg < 4; ++reg) {
        for (int mask = 1; mask < 16; mask <<= 1) {
            pa[reg] += __shfl_xor(pa[reg], mask);
            pb[reg] += __shfl_xor(pb[reg], mask);
        }
    }
    const int g_lo = batch[min(g * 64, N_NODES - 1)];
    const int g_hi = batch[min(g * 64 + 63, N_NODES - 1)];
    float s_lo = 0.f, s_hi = 0.f;
    if (m == 0) {
        #pragma unroll
        for (int reg = 0; reg < 4; ++reg) {
            int row = row0 + q * 4 + reg;
            if (row < N_NODES) {
                atomicAdd(&aArr[row], pa[reg]);
                if (batch[row] == g_lo) s_lo += pb[reg];
                else s_hi += pb[reg];
            }
        }
    }
    for (int mask = 1; mask < 64; mask <<= 1) {
        s_lo += __shfl_xor(s_lo, mask);
        s_hi += __shfl_xor(s_hi, mask);
    }
    if (lane == 0) {
        if (s_lo != 0.f) atomicAdd(&gsum[g_lo], s_lo);
        if (g_hi != g_lo && s_hi != 0.f) atomicAdd(&gsum[g_hi], s_hi);
    }
}

// ---------------------------------------------------------------------------
// K4: edge term sum_e w_e*a[src_e] binned by batch[dst_e] (<=2 graphs per
// bucket -> two register accumulators), then last block computes out[].
// grid = NBUCK*4 (quarter-buckets).
// ---------------------------------------------------------------------------
__global__ __launch_bounds__(256) void k_reduce_final(
    const int2* __restrict__ part, const int* __restrict__ gcursor,
    const float* __restrict__ aArr, const int* __restrict__ batch,
    float* __restrict__ gsum, const int* __restrict__ cntg,
    int* __restrict__ ticket,
    const float* __restrict__ cb3, const float* __restrict__ blin,
    float* __restrict__ out) {
    __shared__ int sbatch[64];
    __shared__ int flag;
    const int t = threadIdx.x;
    const int b = blockIdx.x >> 2;
    const int qtr = blockIdx.x & 3;
    const int nb = b * 64;
    if (t < 64) sbatch[t] = batch[min(nb + t, N_NODES - 1)];
    __syncthreads();
    const int g_lo = sbatch[0];
    const int g_hi = sbatch[63];
    const int base = b * CAP;
    const int cnt = min(gcursor[b], CAP);
    const int i0 = (cnt * qtr) >> 2;
    const int i1 = (cnt * (qtr + 1)) >> 2;
    float s_lo = 0.f, s_hi = 0.f;
    for (int i = i0 + t; i < i1; i += 256) {
        int2 rc = part[base + i];
        float val = __int_as_float(rc.y) * aArr[rc.x & 0xFFFF];
        int dl = (int)((unsigned)rc.x >> 16) - nb;
        if (sbatch[dl] == g_lo) s_lo += val;
        else s_hi += val;
    }
    for (int mask = 1; mask < 64; mask <<= 1) {
        s_lo += __shfl_xor(s_lo, mask);
        s_hi += __shfl_xor(s_hi, mask);
    }
    if ((t & 63) == 0) {
        if (s_lo != 0.f) atomicAdd(&gsum[g_lo], s_lo);
        if (g_hi != g_lo && s_hi != 0.f) atomicAdd(&gsum[g_hi], s_hi);
    }
    __syncthreads();
    if (t == 0) {
        __threadfence();
        flag = (atomicAdd(ticket, 1) == (int)gridDim.x - 1);
    }
    __syncthreads();
    if (flag && t < NGRAPH) {
        __threadfence();
        float S = __hip_atomic_load(&gsum[t], __ATOMIC_RELAXED, __HIP_MEMORY_SCOPE_AGENT);
        int C = cntg[t];
        float denom = (C > 0) ? (float)C : 1.f;
        float v = (S + (float)C * cb3[0]) / denom + blin[0];
        out[t] = (v > 0.f) ? v : 0.f;
    }
}

// ---------------------------------------------------------------------------
extern "C" void kernel_launch(void* const* d_in, const int* in_sizes, int n_in,
                              void* d_out, int out_size, void* d_ws, size_t ws_size,
                              hipStream_t stream) {
    const float* x = (const float*)d_in[0];
    const int* edge_index = (const int*)d_in[1];
    const int* src = edge_index;
    const int* dst = edge_index + N_EDGES;
    const int* batch = (const int*)d_in[2];
    const float* ew = (const float*)d_in[3];
    const float* W1rel = (const float*)d_in[4];
    const float* b1 = (const float*)d_in[5];
    const float* W1root = (const float*)d_in[6];
    const float* W3rel = (const float*)d_in[7];
    const float* b3 = (const float*)d_in[8];
    const float* W3root = (const float*)d_in[9];
    const float* Wlin = (const float*)d_in[10];
    const float* blin = (const float*)d_in[11];
    float* out = (float*)d_out;

    char* w = (char*)d_ws;
    size_t o = 0;
    auto alloc = [&](size_t bytes) -> void* {
        void* p = w + o;
        o += bytes;
        o = (o + 255) & ~(size_t)255;
        return p;
    };
    // zero region: gcursor[313] | ticket | gsum[64] | a[20000]
    const size_t zwords = NBUCK + 1 + NGRAPH + N_NODES;
    char* zbase = (char*)alloc(zwords * 4);
    int* gcursor = (int*)zbase;
    int* ticket = gcursor + NBUCK;
    float* gsum = (float*)(ticket + 1);
    float* aArr = gsum + NGRAPH;

    unsigned int* xb32 = (unsigned int*)alloc((size_t)20032 * 64 * 4);  // bf16 pairs
    unsigned short* wbh = (unsigned short*)alloc((size_t)256 * DIM * 2);
    unsigned short* wbl = (unsigned short*)alloc((size_t)256 * DIM * 2);
    float* z = (float*)alloc((size_t)20032 * DIM * 4);
    int2* part = (int2*)alloc((size_t)NBUCK * CAP * 8);
    float* vrel = (float*)alloc(DIM * 4);
    float* vroot = (float*)alloc(DIM * 4);
    float* cb3 = (float*)alloc(4);
    int* cntg = (int*)alloc(NGRAPH * 4);

    hipMemsetAsync(zbase, 0, zwords * 4, stream);

    k_part_prep<<<NB_PART + NB_XCONV + NB_WCONV + 1, 256, 0, stream>>>(
        src, dst, ew, x, batch, W1rel, W1root, W3rel, W3root, b3, Wlin,
        gcursor, part, xb32, wbh, wbl, vrel, vroot, cb3, cntg);

    k_zgather<<<(N_NODES + 3) / 4, 256, 0, stream>>>(gcursor, part, xb32, z);

    k_gemm_dots<<<dim3(NBUCK, 2), 256, 0, stream>>>(
        x, z, wbh, wbl, b1, vrel, vroot, batch, aArr, gsum);

    k_reduce_final<<<NBUCK * 4, 256, 0, stream>>>(
        part, gcursor, aArr, batch, gsum, cntg, ticket, cb3, blin, out);
}

// Round 15
// 180.056 us; speedup vs baseline: 1.2362x; 1.2362x over previous
//
#include <hip/hip_runtime.h>

#define N_NODES 20000
#define N_EDGES 640000
#define DIM 128
#define NGRAPH 64
#define NBUCK 313          // ceil(20000/64) dst buckets of 64 nodes
#define CAP 2560           // padded records per bucket (mean 2048, 11 sigma)
#define EPB 1024           // edges per partition chunk
#define NB_PART 625        // ceil(640000/1024)
#define NB_WCONV 32
#define NB_GEMM 1252       // 313 row-tiles x 4 col-tiles
#define RED_BLOCKS 512

typedef __attribute__((ext_vector_type(8))) short short8;
typedef __attribute__((ext_vector_type(4))) float floatx4;

__device__ __forceinline__ unsigned int bf16rne(float f) {
    unsigned int u = __float_as_uint(f);
    return (u + 0x7FFFu + ((u >> 16) & 1u)) >> 16;
}

// streaming (read-once) int2 load with non-temporal hint
__device__ __forceinline__ int2 nt_load2(const int2* p) {
    long long v = __builtin_nontemporal_load((const long long*)p);
    int2 r;
    r.x = (int)(v & 0xFFFFFFFFll);
    r.y = (int)(v >> 32);
    return r;
}

// ---------------------------------------------------------------------------
// K1: fused [edge partition into fixed-capacity buckets | weight split-bf16
// convert | params]. No histogram/scan pass: bucket b owns part[b*CAP ..).
// record.x = (dst<<16)|src
// ---------------------------------------------------------------------------
__global__ __launch_bounds__(256) void k_part_prep(
    const int* __restrict__ src, const int* __restrict__ dst,
    const float* __restrict__ ew,
    const float* __restrict__ W1rel, const float* __restrict__ W1root,
    const float* __restrict__ W3rel, const float* __restrict__ W3root,
    const float* __restrict__ b3, const float* __restrict__ Wlin,
    int* __restrict__ gcursor, int2* __restrict__ part,
    unsigned short* __restrict__ wbh, unsigned short* __restrict__ wbl,
    float* __restrict__ vrel, float* __restrict__ vroot, float* __restrict__ cb3) {

    const int t = threadIdx.x;
    const int blk = blockIdx.x;

    if (blk < NB_PART) {
        __shared__ int lhist[NBUCK], lbase[NBUCK], gbase[NBUCK], lcur[NBUCK];
        __shared__ int2 lrec[EPB];   // 8 KB
        for (int i = t; i < NBUCK; i += 256) lhist[i] = 0;
        __syncthreads();
        const int e0 = blk * EPB;
        const int tot = min(EPB, N_EDGES - e0);
        int mys[4], myd[4];
        float myw[4];
        for (int i = 0; i < 4; ++i) {
            int e = e0 + i * 256 + t;
            if (e < N_EDGES) {
                mys[i] = src[e];
                myd[i] = dst[e];
                myw[i] = ew[e];
                atomicAdd(&lhist[myd[i] >> 6], 1);
            } else {
                myd[i] = -1;
            }
        }
        __syncthreads();
        // local exclusive scan over bucket counts (one wave)
        if (t < 64) {
            int carry = 0;
            for (int c = 0; c < 5; ++c) {
                int idx = c * 64 + t;
                int v = (idx < NBUCK) ? lhist[idx] : 0;
                int xv = v;
                for (int s = 1; s < 64; s <<= 1) {
                    int u = __shfl_up(xv, s);
                    if (t >= s) xv += u;
                }
                if (idx < NBUCK) { lbase[idx] = carry + xv - v; lcur[idx] = 0; }
                carry += __shfl(xv, 63);
            }
        }
        __syncthreads();
        // reserve bucket ranges (gcursor[b] counts records; region = b*CAP)
        for (int i = t; i < NBUCK; i += 256) {
            int cnt = lhist[i];
            gbase[i] = cnt ? (i * CAP + atomicAdd(&gcursor[i], cnt)) : 0;
        }
        __syncthreads();
        // bucket-sort into LDS
        for (int i = 0; i < 4; ++i) {
            if (myd[i] >= 0) {
                int bb = myd[i] >> 6;
                int slot = lbase[bb] + atomicAdd(&lcur[bb], 1);
                lrec[slot] = make_int2((myd[i] << 16) | mys[i], __float_as_int(myw[i]));
            }
        }
        __syncthreads();
        // coalesced write-out of bucket runs
        for (int i = t; i < tot; i += 256) {
            int2 rc = lrec[i];
            int bb = ((unsigned)rc.x >> 16) >> 6;
            part[gbase[bb] + (i - lbase[bb])] = rc;
        }
    } else if (blk < NB_PART + NB_WCONV) {
        const int b = blk - NB_PART;
        for (int i = b * 256 + t; i < 256 * DIM; i += NB_WCONV * 256) {
            int n = i >> 7, k = i & 127;
            float v = (n < DIM) ? W1rel[n * DIM + k] : W1root[(n - DIM) * DIM + k];
            unsigned int h = bf16rne(v);
            wbh[i] = (unsigned short)h;
            wbl[i] = (unsigned short)bf16rne(v - __uint_as_float(h << 16));
        }
    } else {
        if (t < 64) {
            for (int kk = 0; kk < 2; ++kk) {
                int k = t + kk * 64;
                float sr = 0.f, so = 0.f;
                for (int h = 0; h < DIM; ++h) {
                    float wl = Wlin[h];
                    sr = fmaf(wl, W3rel[h * DIM + k], sr);
                    so = fmaf(wl, W3root[h * DIM + k], so);
                }
                vrel[k] = sr;
                vroot[k] = so;
            }
            float c = b3[t] * Wlin[t] + b3[t + 64] * Wlin[t + 64];
            for (int m = 32; m > 0; m >>= 1) c += __shfl_xor(c, m);
            if (t == 0) cb3[0] = c;
        }
    }
}

// ---------------------------------------------------------------------------
// K2: fused [in-place bucket counting-sort -> off/nend | split-bf16 MFMA GEMM]
// Both depend only on K1. LDS union 32 KB -> 4 blocks/CU.
// ---------------------------------------------------------------------------
union SMem2 {
    struct { int2 lrec[CAP]; int nh[64], ncur[64]; } s;       // 20992 B
    struct { unsigned short h[64 * DIM], l[64 * DIM]; } g;    // 32768 B
};

__global__ __launch_bounds__(256) void k_sort_gemm(
    const int* __restrict__ gcursor, int2* __restrict__ part,
    int* __restrict__ off, int* __restrict__ nend,
    const float* __restrict__ x,
    const unsigned short* __restrict__ wbh, const unsigned short* __restrict__ wbl,
    const float* __restrict__ b1,
    unsigned short* __restrict__ yb, float* __restrict__ r) {
    __shared__ SMem2 sm;
    const int t = threadIdx.x;

    if (blockIdx.x < NBUCK) {
        // ---------------- bucketsort (in place) ----------------
        const int b = blockIdx.x;
        const int base = b * CAP;
        const int cnt = min(gcursor[b], CAP);
        for (int i = t; i < cnt; i += 256) sm.s.lrec[i] = nt_load2(&part[base + i]);
        if (t < 64) sm.s.nh[t] = 0;
        __syncthreads();
        for (int i = t; i < cnt; i += 256)
            atomicAdd(&sm.s.nh[((unsigned)sm.s.lrec[i].x >> 16) & 63], 1);
        __syncthreads();
        if (t < 64) {
            int v = sm.s.nh[t];
            int xv = v;
            for (int s = 1; s < 64; s <<= 1) {
                int u = __shfl_up(xv, s);
                if (t >= s) xv += u;
            }
            int excl = xv - v;
            sm.s.ncur[t] = excl;
            int node = b * 64 + t;
            if (node < N_NODES) {
                off[node] = base + excl;
                nend[node] = base + excl + v;
            }
        }
        __syncthreads();
        for (int i = t; i < cnt; i += 256) {
            int2 rc = sm.s.lrec[i];
            int dl = ((unsigned)rc.x >> 16) & 63;
            int p = atomicAdd(&sm.s.ncur[dl], 1);
            part[base + p] = make_int2(rc.x & 0xFFFF, rc.y);
        }
    } else {
        // ---------------- GEMM 64-row x 64-col tile ----------------
        const int tile = blockIdx.x - NBUCK;
        const int g = tile >> 2;
        const int col0 = (tile & 3) * 64;
        uint4* sh = (uint4*)sm.g.h;
        uint4* sl = (uint4*)sm.g.l;
        const uint4* gh = (const uint4*)wbh + (size_t)col0 * 16;
        const uint4* gl = (const uint4*)wbl + (size_t)col0 * 16;
        for (int i = t; i < 1024; i += 256) {
            int row = i >> 4, c = i & 15;
            int sc = row * 16 + (c ^ (row & 15));
            sh[sc] = gh[i];
            sl[sc] = gl[i];
        }
        __syncthreads();

        const int lane = t & 63;
        const int m = lane & 15;
        const int q = lane >> 4;
        const int row0 = g * 64 + (t >> 6) * 16;
        const int row = row0 + m;
        const bool ok = row < N_NODES;
        const short8* SH = (const short8*)sm.g.h;
        const short8* SL = (const short8*)sm.g.l;

        floatx4 acc[4];
        #pragma unroll
        for (int i = 0; i < 4; ++i) acc[i] = (floatx4)(0.f);

        #pragma unroll
        for (int kc = 0; kc < 4; ++kc) {
            float4 v0 = make_float4(0.f, 0.f, 0.f, 0.f);
            float4 v1 = make_float4(0.f, 0.f, 0.f, 0.f);
            if (ok) {
                const float4* xp = (const float4*)(x + (size_t)row * DIM + kc * 32 + q * 8);
                v0 = xp[0];
                v1 = xp[1];
            }
            float f[8] = {v0.x, v0.y, v0.z, v0.w, v1.x, v1.y, v1.z, v1.w};
            short8 ah, al;
            #pragma unroll
            for (int i = 0; i < 8; ++i) {
                unsigned int h = bf16rne(f[i]);
                ah[i] = (short)h;
                al[i] = (short)bf16rne(f[i] - __uint_as_float(h << 16));
            }
            #pragma unroll
            for (int nt = 0; nt < 4; ++nt) {
                int nl = nt * 16 + m;
                int cc = (kc * 4 + q) ^ m;
                short8 bh = SH[nl * 16 + cc];
                short8 bl = SL[nl * 16 + cc];
                acc[nt] = __builtin_amdgcn_mfma_f32_16x16x32_bf16(ah, bh, acc[nt], 0, 0, 0);
                acc[nt] = __builtin_amdgcn_mfma_f32_16x16x32_bf16(al, bh, acc[nt], 0, 0, 0);
                acc[nt] = __builtin_amdgcn_mfma_f32_16x16x32_bf16(ah, bl, acc[nt], 0, 0, 0);
            }
        }

        // epilogue: C/D layout col=lane&15, row=q*4+reg
        #pragma unroll
        for (int nt = 0; nt < 4; ++nt) {
            int col = col0 + nt * 16 + m;
            float bias = (col >= DIM) ? b1[col - DIM] : 0.f;
            #pragma unroll
            for (int reg = 0; reg < 4; ++reg) {
                int orow = row0 + q * 4 + reg;
                if (orow < N_NODES) {
                    float v = acc[nt][reg];
                    if (col < DIM)
                        yb[orow * DIM + col] = (unsigned short)bf16rne(v);
                    else
                        r[orow * DIM + (col - DIM)] = v + bias;
                }
            }
        }
    }
}

// ---------------------------------------------------------------------------
// K3: agg — wave per node; 8 y-gathers in flight; h1=relu(agg+r); a,b dots.
// Record stream uses non-temporal loads (read-once) to keep yb L2-resident.
// ---------------------------------------------------------------------------
__global__ __launch_bounds__(256) void k_agg(const unsigned int* __restrict__ yb,
                                             const float2* __restrict__ r2,
                                             const int* __restrict__ off,
                                             const int* __restrict__ nend,
                                             const int2* __restrict__ grec,
                                             const float2* __restrict__ vrel2,
                                             const float2* __restrict__ vroot2,
                                             float* __restrict__ aout,
                                             float* __restrict__ bout) {
    const int lane = threadIdx.x & 63;
    const int node = blockIdx.x * 4 + (threadIdx.x >> 6);
    if (node >= N_NODES) return;

    // hoist independent loads: issue before the gather chain
    const float2 rr = r2[(size_t)node * 64 + lane];
    const float2 vr = vrel2[lane];
    const float2 vo = vroot2[lane];

    int j = off[node];
    const int e1 = nend[node];
    float sx = 0.f, sy = 0.f;
    for (; j + 8 <= e1; j += 8) {
        int2 rc[8];
        #pragma unroll
        for (int u = 0; u < 8; ++u) rc[u] = nt_load2(&grec[j + u]);
        unsigned int v[8];
        #pragma unroll
        for (int u = 0; u < 8; ++u) v[u] = yb[rc[u].x * 64 + lane];
        #pragma unroll
        for (int u = 0; u < 8; ++u) {
            float w = __int_as_float(rc[u].y);
            sx = fmaf(w, __uint_as_float(v[u] << 16), sx);
            sy = fmaf(w, __uint_as_float(v[u] & 0xFFFF0000u), sy);
        }
    }
    for (; j < e1; ++j) {
        int2 rcs = nt_load2(&grec[j]);
        float w = __int_as_float(rcs.y);
        unsigned int vv = yb[rcs.x * 64 + lane];
        sx = fmaf(w, __uint_as_float(vv << 16), sx);
        sy = fmaf(w, __uint_as_float(vv & 0xFFFF0000u), sy);
    }
    float hx = fmaxf(sx + rr.x, 0.f);
    float hy = fmaxf(sy + rr.y, 0.f);
    float pa = hx * vr.x + hy * vr.y;
    float pb = hx * vo.x + hy * vo.y;
    for (int mm = 32; mm > 0; mm >>= 1) {
        pa += __shfl_xor(pa, mm);
        pb += __shfl_xor(pb, mm);
    }
    if (lane == 0) {
        aout[node] = pa;
        bout[node] = pb;
    }
}

// ---------------------------------------------------------------------------
// K4: reduce + final — wave per node; bin by graph; spread partials; last
// block computes out[]
// ---------------------------------------------------------------------------
__global__ __launch_bounds__(256) void k_reduce_final(
    const int2* __restrict__ grec, const int* __restrict__ off,
    const int* __restrict__ nend,
    const float* __restrict__ a, const float* __restrict__ bvec,
    const int* __restrict__ batch,
    float* __restrict__ gpart, int* __restrict__ gpartc,
    int* __restrict__ ticket_red,
    const float* __restrict__ cb3, const float* __restrict__ blin,
    float* __restrict__ out) {
    __shared__ float sbin[NGRAPH];
    __shared__ int cbin[NGRAPH];
    __shared__ int islast;
    const int t = threadIdx.x;
    for (int i = t; i < NGRAPH; i += 256) { sbin[i] = 0.f; cbin[i] = 0; }
    __syncthreads();
    const int lane = t & 63;
    const int gw = blockIdx.x * 4 + (t >> 6);
    const int nw = gridDim.x * 4;
    for (int node = gw; node < N_NODES; node += nw) {
        const int e0 = off[node], e1 = nend[node];
        const float bv = bvec[node];   // hoisted independent load
        float s = 0.f;
        for (int j = e0 + lane; j < e1; j += 64) {
            int2 rc = nt_load2(&grec[j]);
            s = fmaf(__int_as_float(rc.y), a[rc.x], s);
        }
        for (int mm = 32; mm > 0; mm >>= 1) s += __shfl_xor(s, mm);
        if (lane == 0) {
            int g = batch[node];
            atomicAdd(&sbin[g], s + bv);
            atomicAdd(&cbin[g], 1);
        }
    }
    __syncthreads();
    const int slot = blockIdx.x & 63;
    for (int i = t; i < NGRAPH; i += 256) {
        atomicAdd(&gpart[slot * NGRAPH + i], sbin[i]);
        if (cbin[i]) atomicAdd(&gpartc[slot * NGRAPH + i], cbin[i]);
    }
    __syncthreads();
    if (t == 0) {
        __threadfence();
        islast = (atomicAdd(ticket_red, 1) == (int)gridDim.x - 1);
    }
    __syncthreads();
    if (islast) {
        __threadfence();
        if (t < NGRAPH) {
            float S = 0.f;
            int C = 0;
            for (int s2 = 0; s2 < 64; ++s2) {
                S += __hip_atomic_load(&gpart[s2 * NGRAPH + t], __ATOMIC_RELAXED,
                                       __HIP_MEMORY_SCOPE_AGENT);
                C += __hip_atomic_load(&gpartc[s2 * NGRAPH + t], __ATOMIC_RELAXED,
                                       __HIP_MEMORY_SCOPE_AGENT);
            }
            float denom = (C > 0) ? (float)C : 1.f;
            float v = (S + (float)C * cb3[0]) / denom + blin[0];
            out[t] = (v > 0.f) ? v : 0.f;
        }
    }
}

// ---------------------------------------------------------------------------
extern "C" void kernel_launch(void* const* d_in, const int* in_sizes, int n_in,
                              void* d_out, int out_size, void* d_ws, size_t ws_size,
                              hipStream_t stream) {
    const float* x = (const float*)d_in[0];
    const int* edge_index = (const int*)d_in[1];
    const int* src = edge_index;
    const int* dst = edge_index + N_EDGES;
    const int* batch = (const int*)d_in[2];
    const float* ew = (const float*)d_in[3];
    const float* W1rel = (const float*)d_in[4];
    const float* b1 = (const float*)d_in[5];
    const float* W1root = (const float*)d_in[6];
    const float* W3rel = (const float*)d_in[7];
    const float* b3 = (const float*)d_in[8];
    const float* W3root = (const float*)d_in[9];
    const float* Wlin = (const float*)d_in[10];
    const float* blin = (const float*)d_in[11];
    float* out = (float*)d_out;

    char* w = (char*)d_ws;
    size_t o = 0;
    auto alloc = [&](size_t bytes) -> void* {
        void* p = w + o;
        o += bytes;
        o = (o + 255) & ~(size_t)255;
        return p;
    };
    // zero region: gcursor[313] | ticket_red | gpart[64*64] f32 | gpartc[64*64]
    char* zbase = (char*)alloc((NBUCK + 1) * 4 + 64 * NGRAPH * 4 * 2);
    int* gcursor = (int*)zbase;
    int* ticket_red = gcursor + NBUCK;
    float* gpart = (float*)(zbase + (NBUCK + 1) * 4);
    int* gpartc = (int*)(zbase + (NBUCK + 1) * 4 + 64 * NGRAPH * 4);
    const size_t zbytes = (NBUCK + 1) * 4 + 64 * NGRAPH * 4 * 2;

    unsigned short* wbh = (unsigned short*)alloc((size_t)256 * DIM * 2);
    unsigned short* wbl = (unsigned short*)alloc((size_t)256 * DIM * 2);
    unsigned short* yb = (unsigned short*)alloc((size_t)N_NODES * DIM * 2);
    float* r = (float*)alloc((size_t)N_NODES * DIM * 4);
    int2* part = (int2*)alloc((size_t)NBUCK * CAP * 8);   // 6.4 MB padded
    int* off = (int*)alloc((size_t)N_NODES * 4);
    int* nend = (int*)alloc((size_t)N_NODES * 4);
    float* a = (float*)alloc((size_t)N_NODES * 4);
    float* b = (float*)alloc((size_t)N_NODES * 4);
    float* vrel = (float*)alloc(DIM * 4);
    float* vroot = (float*)alloc(DIM * 4);
    float* cb3 = (float*)alloc(4);

    hipMemsetAsync(zbase, 0, zbytes, stream);

    k_part_prep<<<NB_PART + NB_WCONV + 1, 256, 0, stream>>>(
        src, dst, ew, W1rel, W1root, W3rel, W3root, b3, Wlin,
        gcursor, part, wbh, wbl, vrel, vroot, cb3);

    k_sort_gemm<<<NBUCK + NB_GEMM, 256, 0, stream>>>(
        gcursor, part, off, nend, x, wbh, wbl, b1, yb, r);

    k_agg<<<(N_NODES + 3) / 4, 256, 0, stream>>>(
        (const unsigned int*)yb, (const float2*)r, off, nend, part,
        (const float2*)vrel, (const float2*)vroot, a, b);

    k_reduce_final<<<RED_BLOCKS, 256, 0, stream>>>(
        part, off, nend, a, b, batch, gpart, gpartc, ticket_red, cb3, blin, out);
}